// Round 2
// baseline (96103.833 us; speedup 1.0000x reference)
//
#include <hip/hip_runtime.h>
#include <cstddef>

#define BB 32
#define TT 512
#define HH 512
#define NBLK 256
#define NTHR 512

// ---------------------------------------------------------------------------
// Persistent-kernel GRU, 2 layers software-pipelined (layer 1 lags 1 step).
//
// Partition per pipeline step:
//   phase A (gates):  2 layers x 1024 cols x 32 batches = 65536 dots (K=1024)
//     block = (l, chunk): 8 cols x 32 b; wave w owns col j=chunk*8+w, all 32 b
//   phase B (cand):   2 layers x 512 cols x 32 batches = 32768 dots (K=1024)
//     wave w owns col m=chunk*4+(w>>1), 16 batches (half selected by w&1)
//
// K=1024 is split over the 64 lanes: lane L holds k in [16L, 16L+16).
//   - weight slice (16 floats/col) lives in VGPRs for the WHOLE kernel:
//     weights are read from HBM exactly once (vs 12 MB/step before).
//   - input vector [x_t | h] (gates) / [x_t | r*h] (cand): lanes 0..31 read
//     the x/y0 row, lanes 32..63 the h/rh row, 4x float4 each -> fully
//     coalesced 1 KiB per wave instruction.
//   - dot finished with 6-level shfl_xor butterfly; lane 0 does the
//     activation + pointwise update.
//
// Grid sync: single int counter in ws, monotonically increasing target
// (no reset needed). 2 barriers per step, 1026 total.
//
// ws layout (floats): h0@0 [16384], h1@16384 [16384], y0@32768 [2][32][512],
// rh@65536 [2][32][512], uu@98304 [2][32][512], bar(int)@131072. ~512 KB.
// ---------------------------------------------------------------------------

__device__ __forceinline__ float wred(float v) {
#pragma unroll
    for (int m = 1; m < 64; m <<= 1) v += __shfl_xor(v, m, 64);
    return v;  // all lanes hold the sum
}

__device__ __forceinline__ void gbar(int* bar, int target) {
    __threadfence();          // release: make this block's writes visible
    __syncthreads();
    if (threadIdx.x == 0) {
        atomicAdd(bar, 1);    // device-scope by default
        while (__hip_atomic_load(bar, __ATOMIC_RELAXED, __HIP_MEMORY_SCOPE_AGENT) < target)
            __builtin_amdgcn_s_sleep(1);
    }
    __syncthreads();
    __threadfence();          // acquire: invalidate L1 before reading peers' data
}

__global__ __launch_bounds__(NTHR, 1) void rnn_persist(
    const float* __restrict__ x, const int* __restrict__ seq_lens,
    const float* __restrict__ Wg, const float* __restrict__ bg,
    const float* __restrict__ Wc, const float* __restrict__ bc,
    float* __restrict__ out, float* __restrict__ ws) {
    float* h0 = ws;
    float* h1 = ws + 16384;
    float* y0 = ws + 32768;
    float* rh = ws + 65536;
    float* uu = ws + 98304;
    int* bar = (int*)(ws + 131072);

    const int l = blockIdx.x >> 7;        // layer 0 or 1
    const int chunk = blockIdx.x & 127;
    const int w = threadIdx.x >> 6;       // wave 0..7
    const int lane = threadIdx.x & 63;

    const int jg = chunk * 8 + w;             // gates column 0..1023
    const int mc = chunk * 4 + (w >> 1);      // cand column 0..511
    const int bh = (w & 1) * 16;              // cand batch offset

    float* hl = l ? h1 : h0;
    float* rhl = rh + l * (BB * HH);
    float* uul = uu + l * (BB * HH);

    // ---- load per-lane weight slices into registers (once) ----
    // gates: wg[i] = Wg[l][k=lane*16+i][jg]   (Wg is [L][2H][2H], k-major)
    float wg[16];
    {
        const float* p = Wg + ((size_t)l * 1024 + lane * 16) * 1024 + jg;
#pragma unroll
        for (int i = 0; i < 16; ++i) wg[i] = p[(size_t)i * 1024];
    }
    // cand: wc[i] = Wc[l][k=lane*16+i][mc]    (Wc is [L][2H][H])
    float wc[16];
    {
        const float* p = Wc + ((size_t)l * 1024 + lane * 16) * 512 + mc;
#pragma unroll
        for (int i = 0; i < 16; ++i) wc[i] = p[(size_t)i * 512];
    }
    const float bgj = bg[l * 1024 + jg];
    const float bcm = bc[l * 512 + mc];

    int tgt = NBLK;
    for (int t = 0; t <= TT; ++t) {
        const int tt = t - l;
        const bool active = (tt >= 0) && (tt < TT);

        // ---------------- phase A: gates ----------------
        if (active) {
#pragma unroll 2
            for (int b = 0; b < BB; ++b) {
                const float* inrow = l ? (y0 + ((size_t)((tt & 1) * BB + b)) * HH)
                                       : (x + ((size_t)b * TT + tt) * HH);
                const float* vp = (lane < 32) ? (inrow + lane * 16)
                                              : (hl + (size_t)b * HH + (lane - 32) * 16);
                const float4 a0 = *(const float4*)(vp);
                const float4 a1 = *(const float4*)(vp + 4);
                const float4 a2 = *(const float4*)(vp + 8);
                const float4 a3 = *(const float4*)(vp + 12);
                float s0 = a0.x * wg[0] + a0.y * wg[1] + a0.z * wg[2] + a0.w * wg[3];
                float s1 = a1.x * wg[4] + a1.y * wg[5] + a1.z * wg[6] + a1.w * wg[7];
                float s2 = a2.x * wg[8] + a2.y * wg[9] + a2.z * wg[10] + a2.w * wg[11];
                float s3 = a3.x * wg[12] + a3.y * wg[13] + a3.z * wg[14] + a3.w * wg[15];
                const float sum = wred((s0 + s1) + (s2 + s3));
                if (lane == 0) {
                    const float g = 1.0f / (1.0f + __expf(-(sum + bgj)));
                    if (jg < HH)
                        rhl[(size_t)b * HH + jg] = g * hl[(size_t)b * HH + jg];
                    else
                        uul[(size_t)b * HH + (jg - HH)] = g;
                }
            }
        }
        gbar(bar, tgt); tgt += NBLK;

        // ---------------- phase B: candidate + update ----------------
        if (active) {
#pragma unroll 2
            for (int bi = 0; bi < 16; ++bi) {
                const int b = bh + bi;
                const float* inrow = l ? (y0 + ((size_t)((tt & 1) * BB + b)) * HH)
                                       : (x + ((size_t)b * TT + tt) * HH);
                const float* vp = (lane < 32) ? (inrow + lane * 16)
                                              : (rhl + (size_t)b * HH + (lane - 32) * 16);
                const float4 a0 = *(const float4*)(vp);
                const float4 a1 = *(const float4*)(vp + 4);
                const float4 a2 = *(const float4*)(vp + 8);
                const float4 a3 = *(const float4*)(vp + 12);
                float s0 = a0.x * wc[0] + a0.y * wc[1] + a0.z * wc[2] + a0.w * wc[3];
                float s1 = a1.x * wc[4] + a1.y * wc[5] + a1.z * wc[6] + a1.w * wc[7];
                float s2 = a2.x * wc[8] + a2.y * wc[9] + a2.z * wc[10] + a2.w * wc[11];
                float s3 = a3.x * wc[12] + a3.y * wc[13] + a3.z * wc[14] + a3.w * wc[15];
                const float sum = wred((s0 + s1) + (s2 + s3));
                if (lane == 0) {
                    const float c = tanhf(sum + bcm);
                    const float u = uul[(size_t)b * HH + mc];
                    const float hold = hl[(size_t)b * HH + mc];
                    const bool act = tt < seq_lens[b];
                    const float hn = u * hold + (1.0f - u) * c;
                    hl[(size_t)b * HH + mc] = act ? hn : hold;
                    const float yv = act ? hn : 0.0f;
                    if (l == 0)
                        y0[((size_t)((tt & 1) * BB + b)) * HH + mc] = yv;
                    else
                        out[((size_t)b * TT + tt) * HH + mc] = yv;
                }
            }
        }
        gbar(bar, tgt); tgt += NBLK;
    }
}

extern "C" void kernel_launch(void* const* d_in, const int* in_sizes, int n_in,
                              void* d_out, int out_size, void* d_ws, size_t ws_size,
                              hipStream_t stream) {
    const float* x = (const float*)d_in[0];
    const int* seq_lens = (const int*)d_in[1];
    const float* Wg = (const float*)d_in[2];
    const float* bg = (const float*)d_in[3];
    const float* Wc = (const float*)d_in[4];
    const float* bc = (const float*)d_in[5];
    float* out = (float*)d_out;
    float* ws = (float*)d_ws;

    // zero h0, h1 (and y0/rh/uu harmlessly) + barrier counter — every launch,
    // so graph replays are deterministic.
    hipMemsetAsync(ws, 0, (131072 + 1) * sizeof(float), stream);

    rnn_persist<<<NBLK, NTHR, 0, stream>>>(x, seq_lens, Wg, bg, Wc, bc, out, ws);
}

// Round 3
// 16059.123 us; speedup vs baseline: 5.9844x; 5.9844x over previous
//
#include <hip/hip_runtime.h>
#include <cstddef>

#define BB 32
#define TT 512
#define HH 512

// ---------------------------------------------------------------------------
// Dispatch-per-phase GRU (2 layers, software-pipelined: layer 1 lags 1 step).
// Inter-block coherence comes from stream-ordered dispatches (no fences).
//
// Per-step phase A (gates): 2 layers x 1024 cols x 32 batches, K=1024.
//   Block = 256 thr = 4 waves, all on ONE column j of one layer; wave w
//   handles batches [8w, 8w+8). K split over 64 lanes (16 floats each,
//   4x float4); weights held in 16 VGPRs, reused for all 8 batches.
//   Dot finished with a 6-level shfl_xor butterfly; lane 0 activates+stores.
// Per-step phase B (cand+update): 2 x 512 cols x 32 batches, same scheme.
//
// Occupancy: <=64 VGPR (launch_bounds 256,8) -> 8 blocks/CU, 32 waves/CU —
// the latency-hiding round 0 lacked (it ran 4 waves/CU with 2048-FMA chains).
//
// ws layout (floats):
//   h0 @ 0       [32][512]        h1 @ 16384  [32][512]
//   y0 @ 32768   [2][32][512]     rh @ 65536  [2][32][512]
//   uu @ 98304   [2][32][512]
//   WgT @ 131072 [2][1024][1024]  (WgT[l][j][k] = Wg[l][k][j])
//   WcT @ 2228224 [2][512][1024]
// ---------------------------------------------------------------------------

template <int R, int C>
__global__ __launch_bounds__(256) void transpose_k(const float* __restrict__ src,
                                                   float* __restrict__ dst) {
    __shared__ float tile[32][33];
    const int tx = threadIdx.x & 31;
    const int ty = threadIdx.x >> 5;
    const int tiles_c = C / 32;
    const int bc_ = blockIdx.x % tiles_c;
    const int br_ = blockIdx.x / tiles_c;
    const int r0 = br_ * 32, c0 = bc_ * 32;
#pragma unroll
    for (int k = 0; k < 32; k += 8)
        tile[ty + k][tx] = src[(size_t)(r0 + ty + k) * C + (c0 + tx)];
    __syncthreads();
#pragma unroll
    for (int k = 0; k < 32; k += 8)
        dst[(size_t)(c0 + ty + k) * R + (r0 + tx)] = tile[tx][ty + k];
}

__device__ __forceinline__ float wred(float v) {
#pragma unroll
    for (int m = 1; m < 64; m <<= 1) v += __shfl_xor(v, m, 64);
    return v;
}

__global__ __launch_bounds__(256, 8) void gates_k(
    const float* __restrict__ x, const float* __restrict__ y0,
    const float* __restrict__ h0, const float* __restrict__ h1,
    const float* __restrict__ WgT, const float* __restrict__ bg,
    float* __restrict__ rh, float* __restrict__ uu, int t) {
    const int l = blockIdx.x >> 10;          // layer
    const int tt = t - l;
    if (tt < 0 || tt >= TT) return;
    const int j = blockIdx.x & 1023;         // gate column
    const int w = threadIdx.x >> 6;          // wave -> batch group
    const int lane = threadIdx.x & 63;

    const float* __restrict__ hl = (l ? h1 : h0);
    float* __restrict__ rhl = rh + (size_t)l * (BB * HH);
    float* __restrict__ uul = uu + (size_t)l * (BB * HH);

    // per-lane weight slice: k in [lane*16, lane*16+16)
    const float* wp = WgT + ((size_t)l * 1024 + j) * 1024 + lane * 16;
    const float4 w0 = ((const float4*)wp)[0];
    const float4 w1 = ((const float4*)wp)[1];
    const float4 w2 = ((const float4*)wp)[2];
    const float4 w3 = ((const float4*)wp)[3];
    const float bgj = bg[l * 1024 + j];

#pragma unroll 2
    for (int bi = 0; bi < 8; ++bi) {
        const int b = w * 8 + bi;
        const float* inrow = l ? (y0 + ((size_t)((tt & 1) * BB + b)) * HH)
                               : (x + ((size_t)b * TT + tt) * HH);
        const float* vp = (lane < 32) ? (inrow + lane * 16)
                                      : (hl + (size_t)b * HH + (lane - 32) * 16);
        const float4 a0 = ((const float4*)vp)[0];
        const float4 a1 = ((const float4*)vp)[1];
        const float4 a2 = ((const float4*)vp)[2];
        const float4 a3 = ((const float4*)vp)[3];
        float s0 = a0.x * w0.x + a0.y * w0.y + a0.z * w0.z + a0.w * w0.w;
        float s1 = a1.x * w1.x + a1.y * w1.y + a1.z * w1.z + a1.w * w1.w;
        float s2 = a2.x * w2.x + a2.y * w2.y + a2.z * w2.z + a2.w * w2.w;
        float s3 = a3.x * w3.x + a3.y * w3.y + a3.z * w3.z + a3.w * w3.w;
        const float sum = wred((s0 + s1) + (s2 + s3));
        if (lane == 0) {
            const float g = 1.0f / (1.0f + __expf(-(sum + bgj)));
            if (j < HH)
                rhl[(size_t)b * HH + j] = g * hl[(size_t)b * HH + j];
            else
                uul[(size_t)b * HH + (j - HH)] = g;
        }
    }
}

__global__ __launch_bounds__(256, 8) void cand_k(
    const float* __restrict__ x, float* __restrict__ y0,
    float* __restrict__ h0, float* __restrict__ h1,
    const float* __restrict__ WcT, const float* __restrict__ bc,
    const float* __restrict__ rh, const float* __restrict__ uu,
    const int* __restrict__ seq_lens, float* __restrict__ out, int t) {
    const int l = blockIdx.x >> 9;           // layer
    const int tt = t - l;
    if (tt < 0 || tt >= TT) return;
    const int m = blockIdx.x & 511;          // candidate column
    const int w = threadIdx.x >> 6;
    const int lane = threadIdx.x & 63;

    float* __restrict__ hl = (l ? h1 : h0);
    const float* __restrict__ rhl = rh + (size_t)l * (BB * HH);
    const float* __restrict__ uul = uu + (size_t)l * (BB * HH);

    const float* wp = WcT + ((size_t)l * 512 + m) * 1024 + lane * 16;
    const float4 w0 = ((const float4*)wp)[0];
    const float4 w1 = ((const float4*)wp)[1];
    const float4 w2 = ((const float4*)wp)[2];
    const float4 w3 = ((const float4*)wp)[3];
    const float bcm = bc[l * 512 + m];

#pragma unroll 2
    for (int bi = 0; bi < 8; ++bi) {
        const int b = w * 8 + bi;
        const float* inrow = l ? (y0 + ((size_t)((tt & 1) * BB + b)) * HH)
                               : (x + ((size_t)b * TT + tt) * HH);
        const float* vp = (lane < 32) ? (inrow + lane * 16)
                                      : (rhl + (size_t)b * HH + (lane - 32) * 16);
        const float4 a0 = ((const float4*)vp)[0];
        const float4 a1 = ((const float4*)vp)[1];
        const float4 a2 = ((const float4*)vp)[2];
        const float4 a3 = ((const float4*)vp)[3];
        float s0 = a0.x * w0.x + a0.y * w0.y + a0.z * w0.z + a0.w * w0.w;
        float s1 = a1.x * w1.x + a1.y * w1.y + a1.z * w1.z + a1.w * w1.w;
        float s2 = a2.x * w2.x + a2.y * w2.y + a2.z * w2.z + a2.w * w2.w;
        float s3 = a3.x * w3.x + a3.y * w3.y + a3.z * w3.z + a3.w * w3.w;
        const float sum = wred((s0 + s1) + (s2 + s3));
        if (lane == 0) {
            const float c = tanhf(sum + bcm);
            const float u = uul[(size_t)b * HH + m];
            const float hold = hl[(size_t)b * HH + m];
            const bool act = tt < seq_lens[b];
            const float hn = u * hold + (1.0f - u) * c;
            hl[(size_t)b * HH + m] = act ? hn : hold;
            const float yv = act ? hn : 0.0f;
            if (l == 0)
                y0[((size_t)((tt & 1) * BB + b)) * HH + m] = yv;
            else
                out[((size_t)b * TT + tt) * HH + m] = yv;
        }
    }
}

extern "C" void kernel_launch(void* const* d_in, const int* in_sizes, int n_in,
                              void* d_out, int out_size, void* d_ws, size_t ws_size,
                              hipStream_t stream) {
    const float* x = (const float*)d_in[0];
    const int* seq_lens = (const int*)d_in[1];
    const float* Wg = (const float*)d_in[2];
    const float* bg = (const float*)d_in[3];
    const float* Wc = (const float*)d_in[4];
    const float* bc = (const float*)d_in[5];
    float* out = (float*)d_out;
    float* ws = (float*)d_ws;

    float* h0 = ws;
    float* h1 = ws + 16384;
    float* y0 = ws + 32768;
    float* rhb = ws + 65536;
    float* uub = ws + 98304;
    float* WgT = ws + 131072;
    float* WcT = ws + 2228224;

    // zero initial hidden states every launch (graph replays deterministic)
    hipMemsetAsync(ws, 0, 2 * BB * HH * sizeof(float), stream);

    transpose_k<1024, 1024><<<1024, 256, 0, stream>>>(Wg, WgT);
    transpose_k<1024, 1024><<<1024, 256, 0, stream>>>(Wg + 1024 * 1024, WgT + 1024 * 1024);
    transpose_k<1024, 512><<<512, 256, 0, stream>>>(Wc, WcT);
    transpose_k<1024, 512><<<512, 256, 0, stream>>>(Wc + 1024 * 512, WcT + 512 * 1024);

    for (int t = 0; t <= TT; ++t) {
        gates_k<<<2048, 256, 0, stream>>>(x, y0, h0, h1, WgT, bg, rhb, uub, t);
        cand_k<<<1024, 256, 0, stream>>>(x, y0, h0, h1, WcT, bc, rhb, uub, seq_lens, out, t);
    }
}

// Round 4
// 12028.573 us; speedup vs baseline: 7.9896x; 1.3351x over previous
//
#include <hip/hip_runtime.h>
#include <cstddef>

#define BB 32
#define TT 512
#define HH 512

// ---------------------------------------------------------------------------
// Dispatch-per-phase GRU (2 layers, software-pipelined: layer 1 lags 1 step).
// Inter-block coherence via stream-ordered dispatches (no fences).
//
// Round-3 change: amortize input fetches across columns held in registers.
//   gates: wave = 4 cols x 8 batches  (input float4 reused 4x; 64 wt VGPRs)
//   cand : wave = 2 cols x 8 batches
// K=1024 split over 64 lanes (16 floats each, 4x float4); dot finished with
// 6-level shfl_xor butterfly on all col-sums; lane 0 does activation + vector
// stores (cols adjacent -> float4/float2 stores).
//
// ws layout (floats):
//   h0 @ 0       [32][512]        h1 @ 16384  [32][512]
//   y0 @ 32768   [2][32][512]     rh @ 65536  [2][32][512]
//   uu @ 98304   [2][32][512]
//   WgT @ 131072 [2][1024][1024]  (WgT[l][j][k] = Wg[l][k][j])
//   WcT @ 2228224 [2][512][1024]
// ---------------------------------------------------------------------------

template <int R, int C>
__global__ __launch_bounds__(256) void transpose_k(const float* __restrict__ src,
                                                   float* __restrict__ dst) {
    __shared__ float tile[32][33];
    const int tx = threadIdx.x & 31;
    const int ty = threadIdx.x >> 5;
    const int tiles_c = C / 32;
    const int bc_ = blockIdx.x % tiles_c;
    const int br_ = blockIdx.x / tiles_c;
    const int r0 = br_ * 32, c0 = bc_ * 32;
#pragma unroll
    for (int k = 0; k < 32; k += 8)
        tile[ty + k][tx] = src[(size_t)(r0 + ty + k) * C + (c0 + tx)];
    __syncthreads();
#pragma unroll
    for (int k = 0; k < 32; k += 8)
        dst[(size_t)(c0 + ty + k) * R + (r0 + tx)] = tile[tx][ty + k];
}

__device__ __forceinline__ float dot16(const float4& a0, const float4& a1,
                                       const float4& a2, const float4& a3,
                                       const float4& w0, const float4& w1,
                                       const float4& w2, const float4& w3) {
    float s0 = a0.x * w0.x + a0.y * w0.y + a0.z * w0.z + a0.w * w0.w;
    float s1 = a1.x * w1.x + a1.y * w1.y + a1.z * w1.z + a1.w * w1.w;
    float s2 = a2.x * w2.x + a2.y * w2.y + a2.z * w2.z + a2.w * w2.w;
    float s3 = a3.x * w3.x + a3.y * w3.y + a3.z * w3.z + a3.w * w3.w;
    return (s0 + s1) + (s2 + s3);
}

// gates: grid = 2 layers * 256 col-groups (4 cols each) = 512 blocks, 256 thr.
__global__ __launch_bounds__(256, 2) void gates_k(
    const float* __restrict__ x, const float* __restrict__ y0,
    const float* __restrict__ h0, const float* __restrict__ h1,
    const float* __restrict__ WgT, const float* __restrict__ bg,
    float* __restrict__ rh, float* __restrict__ uu, int t) {
    const int l = blockIdx.x >> 8;
    const int tt = t - l;
    if (tt < 0 || tt >= TT) return;
    const int j0 = (blockIdx.x & 255) * 4;   // 4 adjacent gate columns
    const int w = threadIdx.x >> 6;
    const int lane = threadIdx.x & 63;

    const float* __restrict__ hl = (l ? h1 : h0);
    float* __restrict__ rhl = rh + (size_t)l * (BB * HH);
    float* __restrict__ uul = uu + (size_t)l * (BB * HH);

    // 4 columns' weight slices: 16 float4 = 64 VGPRs, held all kernel.
    const float* wp = WgT + ((size_t)l * 1024 + j0) * 1024 + lane * 16;
    float4 W[4][4];
#pragma unroll
    for (int c = 0; c < 4; ++c)
#pragma unroll
        for (int q = 0; q < 4; ++q)
            W[c][q] = ((const float4*)(wp + (size_t)c * 1024))[q];
    const float4 bgv = *(const float4*)(bg + l * 1024 + j0);

    for (int bi = 0; bi < 8; ++bi) {
        const int b = w * 8 + bi;
        const float* inrow = l ? (y0 + ((size_t)((tt & 1) * BB + b)) * HH)
                               : (x + ((size_t)b * TT + tt) * HH);
        const float* vp = (lane < 32) ? (inrow + lane * 16)
                                      : (hl + (size_t)b * HH + (lane - 32) * 16);
        const float4 a0 = ((const float4*)vp)[0];
        const float4 a1 = ((const float4*)vp)[1];
        const float4 a2 = ((const float4*)vp)[2];
        const float4 a3 = ((const float4*)vp)[3];
        float s0 = dot16(a0, a1, a2, a3, W[0][0], W[0][1], W[0][2], W[0][3]);
        float s1 = dot16(a0, a1, a2, a3, W[1][0], W[1][1], W[1][2], W[1][3]);
        float s2 = dot16(a0, a1, a2, a3, W[2][0], W[2][1], W[2][2], W[2][3]);
        float s3 = dot16(a0, a1, a2, a3, W[3][0], W[3][1], W[3][2], W[3][3]);
#pragma unroll
        for (int m = 1; m < 64; m <<= 1) {
            s0 += __shfl_xor(s0, m, 64);
            s1 += __shfl_xor(s1, m, 64);
            s2 += __shfl_xor(s2, m, 64);
            s3 += __shfl_xor(s3, m, 64);
        }
        if (lane == 0) {
            float4 g;
            g.x = 1.0f / (1.0f + __expf(-(s0 + bgv.x)));
            g.y = 1.0f / (1.0f + __expf(-(s1 + bgv.y)));
            g.z = 1.0f / (1.0f + __expf(-(s2 + bgv.z)));
            g.w = 1.0f / (1.0f + __expf(-(s3 + bgv.w)));
            if (j0 < HH) {  // r-gate block (all 4 cols on same side of 512)
                const float4 hv = *(const float4*)(hl + (size_t)b * HH + j0);
                float4 r;
                r.x = g.x * hv.x; r.y = g.y * hv.y;
                r.z = g.z * hv.z; r.w = g.w * hv.w;
                *(float4*)(rhl + (size_t)b * HH + j0) = r;
            } else {
                *(float4*)(uul + (size_t)b * HH + (j0 - HH)) = g;
            }
        }
    }
}

// cand: grid = 2 layers * 256 col-groups (2 cols each) = 512 blocks, 256 thr.
__global__ __launch_bounds__(256, 2) void cand_k(
    const float* __restrict__ x, float* __restrict__ y0,
    float* __restrict__ h0, float* __restrict__ h1,
    const float* __restrict__ WcT, const float* __restrict__ bc,
    const float* __restrict__ rh, const float* __restrict__ uu,
    const int* __restrict__ seq_lens, float* __restrict__ out, int t) {
    const int l = blockIdx.x >> 8;
    const int tt = t - l;
    if (tt < 0 || tt >= TT) return;
    const int m0 = (blockIdx.x & 255) * 2;   // 2 adjacent candidate columns
    const int w = threadIdx.x >> 6;
    const int lane = threadIdx.x & 63;

    float* __restrict__ hl = (l ? h1 : h0);
    const float* __restrict__ rhl = rh + (size_t)l * (BB * HH);
    const float* __restrict__ uul = uu + (size_t)l * (BB * HH);

    const float* wp = WcT + ((size_t)l * 512 + m0) * 1024 + lane * 16;
    float4 W[2][4];
#pragma unroll
    for (int c = 0; c < 2; ++c)
#pragma unroll
        for (int q = 0; q < 4; ++q)
            W[c][q] = ((const float4*)(wp + (size_t)c * 1024))[q];
    const float2 bcv = *(const float2*)(bc + l * 512 + m0);

    for (int bi = 0; bi < 8; ++bi) {
        const int b = w * 8 + bi;
        const float* inrow = l ? (y0 + ((size_t)((tt & 1) * BB + b)) * HH)
                               : (x + ((size_t)b * TT + tt) * HH);
        const float* vp = (lane < 32) ? (inrow + lane * 16)
                                      : (rhl + (size_t)b * HH + (lane - 32) * 16);
        const float4 a0 = ((const float4*)vp)[0];
        const float4 a1 = ((const float4*)vp)[1];
        const float4 a2 = ((const float4*)vp)[2];
        const float4 a3 = ((const float4*)vp)[3];
        float s0 = dot16(a0, a1, a2, a3, W[0][0], W[0][1], W[0][2], W[0][3]);
        float s1 = dot16(a0, a1, a2, a3, W[1][0], W[1][1], W[1][2], W[1][3]);
#pragma unroll
        for (int m = 1; m < 64; m <<= 1) {
            s0 += __shfl_xor(s0, m, 64);
            s1 += __shfl_xor(s1, m, 64);
        }
        if (lane == 0) {
            const float c0v = tanhf(s0 + bcv.x);
            const float c1v = tanhf(s1 + bcv.y);
            const float2 uv = *(const float2*)(uul + (size_t)b * HH + m0);
            const float2 hv = *(const float2*)(hl + (size_t)b * HH + m0);
            const bool act = tt < seq_lens[b];
            float2 hn;
            hn.x = uv.x * hv.x + (1.0f - uv.x) * c0v;
            hn.y = uv.y * hv.y + (1.0f - uv.y) * c1v;
            float2 hstore, ystore;
            hstore.x = act ? hn.x : hv.x;
            hstore.y = act ? hn.y : hv.y;
            ystore.x = act ? hn.x : 0.0f;
            ystore.y = act ? hn.y : 0.0f;
            *(float2*)(hl + (size_t)b * HH + m0) = hstore;
            if (l == 0)
                *(float2*)(y0 + ((size_t)((tt & 1) * BB + b)) * HH + m0) = ystore;
            else
                *(float2*)(out + ((size_t)b * TT + tt) * HH + m0) = ystore;
        }
    }
}

extern "C" void kernel_launch(void* const* d_in, const int* in_sizes, int n_in,
                              void* d_out, int out_size, void* d_ws, size_t ws_size,
                              hipStream_t stream) {
    const float* x = (const float*)d_in[0];
    const int* seq_lens = (const int*)d_in[1];
    const float* Wg = (const float*)d_in[2];
    const float* bg = (const float*)d_in[3];
    const float* Wc = (const float*)d_in[4];
    const float* bc = (const float*)d_in[5];
    float* out = (float*)d_out;
    float* ws = (float*)d_ws;

    float* h0 = ws;
    float* h1 = ws + 16384;
    float* y0 = ws + 32768;
    float* rhb = ws + 65536;
    float* uub = ws + 98304;
    float* WgT = ws + 131072;
    float* WcT = ws + 2228224;

    // zero initial hidden states every launch (graph replays deterministic)
    hipMemsetAsync(ws, 0, 2 * BB * HH * sizeof(float), stream);

    transpose_k<1024, 1024><<<1024, 256, 0, stream>>>(Wg, WgT);
    transpose_k<1024, 1024><<<1024, 256, 0, stream>>>(Wg + 1024 * 1024, WgT + 1024 * 1024);
    transpose_k<1024, 512><<<512, 256, 0, stream>>>(Wc, WcT);
    transpose_k<1024, 512><<<512, 256, 0, stream>>>(Wc + 1024 * 512, WcT + 512 * 1024);

    for (int t = 0; t <= TT; ++t) {
        gates_k<<<512, 256, 0, stream>>>(x, y0, h0, h1, WgT, bg, rhb, uub, t);
        cand_k<<<512, 256, 0, stream>>>(x, y0, h0, h1, WcT, bc, rhb, uub, seq_lens, out, t);
    }
}